// Round 1
// baseline (1334.030 us; speedup 1.0000x reference)
//
#include <hip/hip_runtime.h>

#define NN 4096
#define DD 64
#define RR 128
#define GG 32
constexpr float BIGF = 1e9f;

// ---- workspace layout (uint32 indices into d_ws) ----
constexpr int WS_HIST  = 0;                 // 4 levels x 256 bins
constexpr int WS_STATE = 1024;              // [0]=prefix key bits, [1]=rem
constexpr int WS_ECNT  = 1028;              // edge counter
constexpr int WS_EQCNT = 1029;              // equal-key counter
constexpr int WS_EI    = 2048;
constexpr int WS_EJ    = WS_EI + 16384;
constexpr int WS_EV    = WS_EJ + 16384;
constexpr int WS_EQ    = WS_EV + 16384;
constexpr int EDGE_CAP = 16384;
constexpr int EQ_CAP   = 4096;

__global__ void init_kernel(unsigned* ws, const int* budget) {
  int t = threadIdx.x;
  if (t < 1024) ws[t] = 0;                  // all 4 histograms
  if (t == 0) {
    ws[WS_STATE]     = 0;                   // prefix
    ws[WS_STATE + 1] = (unsigned)budget[0]; // rem = k
    ws[WS_ECNT]      = 0;
    ws[WS_EQCNT]     = 0;
  }
}

// swizzled float4-group index within a 128x64 LDS tile
__device__ __forceinline__ int swz(int row, int g) { return g ^ ((row >> 3) & 7); }

// adj = relu(tanh(E E^T)), written dense to d_out (used as scratch)
__global__ __launch_bounds__(256) void gemm_adj_kernel(const float* __restrict__ E,
                                                       float* __restrict__ adj) {
  __shared__ float As[RR * DD];
  __shared__ float Bs[RR * DD];
  float4* As4 = (float4*)As;
  float4* Bs4 = (float4*)Bs;
  const float4* E4 = (const float4*)E;
  const int bi = blockIdx.y * RR;
  const int bj = blockIdx.x * RR;
  const int tid = threadIdx.x;

  for (int e = tid; e < RR * (DD / 4); e += 256) {
    int r = e >> 4, g = e & 15;
    As4[r * 16 + swz(r, g)] = E4[(bi + r) * 16 + g];
    Bs4[r * 16 + swz(r, g)] = E4[(bj + r) * 16 + g];
  }
  __syncthreads();

  const int i0 = (tid >> 4) * 8;
  const int j0 = (tid & 15) * 8;
  float acc[8][8] = {};
#pragma unroll
  for (int g = 0; g < 16; ++g) {
    float4 av[8], bv[8];
#pragma unroll
    for (int r = 0; r < 8; ++r) av[r] = As4[(i0 + r) * 16 + swz(i0 + r, g)];
#pragma unroll
    for (int c = 0; c < 8; ++c) bv[c] = Bs4[(j0 + c) * 16 + swz(j0 + c, g)];
#pragma unroll
    for (int r = 0; r < 8; ++r)
#pragma unroll
      for (int c = 0; c < 8; ++c) {
        acc[r][c] += av[r].x * bv[c].x;
        acc[r][c] += av[r].y * bv[c].y;
        acc[r][c] += av[r].z * bv[c].z;
        acc[r][c] += av[r].w * bv[c].w;
      }
  }
#pragma unroll
  for (int r = 0; r < 8; ++r) {
    size_t o = (size_t)(bi + i0 + r) * NN + bj + j0;
    float4 o0, o1;
    float* p0 = &o0.x;
    float* p1 = &o1.x;
#pragma unroll
    for (int c = 0; c < 4; ++c) {
      float t0 = tanhf(acc[r][c]);     p0[c] = t0 > 0.f ? t0 : 0.f;
      float t1 = tanhf(acc[r][c + 4]); p1[c] = t1 > 0.f ? t1 : 0.f;
    }
    *(float4*)(adj + o)     = o0;
    *(float4*)(adj + o + 4) = o1;
  }
}

// Per-region Prim, exact replica of reference semantics (argmin lowest-index
// tie-break, BIG-tie wasted iterations, in_tree set before relaxation).
__global__ __launch_bounds__(128) void mst_kernel(const float* __restrict__ adj, unsigned* ws) {
  const int g = blockIdx.x;
  const int t = threadIdx.x;
  const int base = g * RR;
  __shared__ float swk[2];
  __shared__ int   swi[2];
  int*   ei = (int*)(ws + WS_EI);
  int*   ej = (int*)(ws + WS_EJ);
  float* ev = (float*)(ws + WS_EV);

  float a0 = adj[(size_t)base * NN + base + t];
  bool in_tree = (t == 0);
  float key = (t != 0 && a0 > 0.f) ? -a0 : BIGF;
  int parent = 0;
  const int lane = t & 63, wid = t >> 6;

  for (int it = 0; it < RR - 1; ++it) {
    float km = in_tree ? BIGF : key;
    float k_ = km; int i_ = t;
#pragma unroll
    for (int off = 32; off > 0; off >>= 1) {
      float ok = __shfl_down(k_, off);
      int   oi = __shfl_down(i_, off);
      if (ok < k_ || (ok == k_ && oi < i_)) { k_ = ok; i_ = oi; }
    }
    if (lane == 0) { swk[wid] = k_; swi[wid] = i_; }
    __syncthreads();
    float k0 = swk[0], k1 = swk[1];
    int idx0 = swi[0], idx1 = swi[1];
    __syncthreads();
    int u; float kmu;
    if (k1 < k0 || (k1 == k0 && idx1 < idx0)) { kmu = k1; u = idx1; }
    else                                      { kmu = k0; u = idx0; }

    if (t == u) {
      if (kmu < 0.5f * BIGF) {
        unsigned slot = atomicAdd(ws + WS_ECNT, 1u);
        if (slot < EDGE_CAP) { ei[slot] = base + u; ej[slot] = base + parent; ev[slot] = -kmu; }
      }
      in_tree = true;
    }
    float av = adj[(size_t)(base + u) * NN + base + t];
    float w = (av > 0.f && t != u) ? -av : BIGF;
    if (!in_tree && w < key) { key = w; parent = u; }
  }
}

// Radix-select histogram over candidate values (j>i, different region, v>0)
__global__ __launch_bounds__(256) void hist_kernel(const float* __restrict__ adj,
                                                   unsigned* ws, int level) {
  __shared__ unsigned h[256];
  h[threadIdx.x] = 0;
  __syncthreads();
  const unsigned prefix = ws[WS_STATE];
  const float4* a4 = (const float4*)adj;
  const long total4 = (long)NN * NN / 4;
  const long stride = (long)gridDim.x * blockDim.x;
  for (long e = (long)blockIdx.x * blockDim.x + threadIdx.x; e < total4; e += stride) {
    float4 v = a4[e];
    int b = (int)(e << 2);
    int i = b >> 12, j0 = b & 4095, ri_ = i >> 7;
    float comp[4] = {v.x, v.y, v.z, v.w};
#pragma unroll
    for (int c = 0; c < 4; ++c) {
      int j = j0 + c;
      float x = comp[c];
      if (j <= i || ((j >> 7) == ri_) || !(x > 0.f)) continue;
      unsigned key = __float_as_uint(x);
      if (level > 0 && (key >> (32 - 8 * level)) != prefix) continue;
      unsigned d = (key >> (24 - 8 * level)) & 255u;
      atomicAdd(&h[d], 1u);
    }
  }
  __syncthreads();
  unsigned c = h[threadIdx.x];
  if (c) atomicAdd(&ws[WS_HIST + level * 256 + threadIdx.x], c);
}

__global__ void scan_kernel(unsigned* ws, int level) {
  if (threadIdx.x != 0) return;
  unsigned* h = ws + WS_HIST + level * 256;
  unsigned rem = ws[WS_STATE + 1];
  unsigned prefix = ws[WS_STATE];
  unsigned cum = 0;
  int chosen = 0;
  for (int d = 255; d >= 0; --d) {
    unsigned c = h[d];
    if (cum + c >= rem) { chosen = d; break; }
    cum += c;
  }
  ws[WS_STATE]     = (prefix << 8) | (unsigned)chosen;
  ws[WS_STATE + 1] = rem - cum;
}

__global__ __launch_bounds__(256) void select_kernel(const float* __restrict__ adj, unsigned* ws) {
  const unsigned kth = ws[WS_STATE];
  int*   ei = (int*)(ws + WS_EI);
  int*   ej = (int*)(ws + WS_EJ);
  float* ev = (float*)(ws + WS_EV);
  const float4* a4 = (const float4*)adj;
  const long total4 = (long)NN * NN / 4;
  const long stride = (long)gridDim.x * blockDim.x;
  for (long e = (long)blockIdx.x * blockDim.x + threadIdx.x; e < total4; e += stride) {
    float4 v = a4[e];
    int b = (int)(e << 2);
    int i = b >> 12, j0 = b & 4095, ri_ = i >> 7;
    float comp[4] = {v.x, v.y, v.z, v.w};
#pragma unroll
    for (int c = 0; c < 4; ++c) {
      int j = j0 + c;
      float x = comp[c];
      if (j <= i || ((j >> 7) == ri_) || !(x > 0.f)) continue;
      unsigned key = __float_as_uint(x);
      if (key > kth) {
        unsigned slot = atomicAdd(ws + WS_ECNT, 1u);
        if (slot < EDGE_CAP) { ei[slot] = i; ej[slot] = j; ev[slot] = x; }
      } else if (key == kth) {
        unsigned s2 = atomicAdd(ws + WS_EQCNT, 1u);
        if (s2 < EQ_CAP) ws[WS_EQ + s2] = (unsigned)((i << 12) | j);
      }
    }
  }
}

// resolve ties at the k-th value: take the `rem` lowest flat indices (lax.top_k stability)
__global__ void eqres_kernel(unsigned* ws) {
  if (threadIdx.x != 0 || blockIdx.x != 0) return;
  unsigned need = ws[WS_STATE + 1];
  unsigned n = ws[WS_EQCNT]; if (n > EQ_CAP) n = EQ_CAP;
  unsigned kth = ws[WS_STATE];
  unsigned* eq = ws + WS_EQ;
  int*   ei = (int*)(ws + WS_EI);
  int*   ej = (int*)(ws + WS_EJ);
  float* ev = (float*)(ws + WS_EV);
  for (unsigned s = 0; s < need && s < n; ++s) {
    unsigned best = 0xFFFFFFFFu; int bpos = -1;
    for (unsigned e = 0; e < n; ++e)
      if (eq[e] < best) { best = eq[e]; bpos = (int)e; }
    if (bpos < 0) break;
    eq[bpos] = 0xFFFFFFFFu;
    unsigned slot = atomicAdd(ws + WS_ECNT, 1u);
    if (slot < EDGE_CAP) {
      ei[slot] = (int)(best >> 12);
      ej[slot] = (int)(best & 4095u);
      ev[slot] = __uint_as_float(kth);
    }
  }
}

__global__ void scatter_kernel(const unsigned* __restrict__ ws, float* __restrict__ out) {
  unsigned cnt = ws[WS_ECNT];
  if (cnt > EDGE_CAP) cnt = EDGE_CAP;
  const int*   ei = (const int*)(ws + WS_EI);
  const int*   ej = (const int*)(ws + WS_EJ);
  const float* ev = (const float*)(ws + WS_EV);
  for (unsigned e = blockIdx.x * blockDim.x + threadIdx.x; e < cnt;
       e += gridDim.x * blockDim.x) {
    int i = ei[e], j = ej[e];
    float v = ev[e];
    out[(size_t)i * NN + j] = v;
    out[(size_t)j * NN + i] = v;
  }
}

extern "C" void kernel_launch(void* const* d_in, const int* in_sizes, int n_in,
                              void* d_out, int out_size, void* d_ws, size_t ws_size,
                              hipStream_t stream) {
  const float* E      = (const float*)d_in[0];
  const int*   budget = (const int*)d_in[2];   // inter_mask (d_in[1]) derived from indices instead
  float*    adj = (float*)d_out;               // d_out doubles as adj scratch
  unsigned* ws  = (unsigned*)d_ws;

  init_kernel<<<1, 1024, 0, stream>>>(ws, budget);
  gemm_adj_kernel<<<dim3(NN / RR, NN / RR), 256, 0, stream>>>(E, adj);
  mst_kernel<<<GG, RR, 0, stream>>>(adj, ws);
  for (int lvl = 0; lvl < 4; ++lvl) {
    hist_kernel<<<2048, 256, 0, stream>>>(adj, ws, lvl);
    scan_kernel<<<1, 64, 0, stream>>>(ws, lvl);
  }
  select_kernel<<<2048, 256, 0, stream>>>(adj, ws);
  eqres_kernel<<<1, 64, 0, stream>>>(ws);
  hipMemsetAsync(d_out, 0, (size_t)NN * NN * sizeof(float), stream);
  scatter_kernel<<<64, 256, 0, stream>>>(ws, adj);
}

// Round 2
// 503.790 us; speedup vs baseline: 2.6480x; 2.6480x over previous
//
#include <hip/hip_runtime.h>

#define NN 4096
#define DD 64
#define RR 128
#define GG 32
constexpr float BIGF = 1e9f;

// ---- workspace layout (u32 words) ----
constexpr int WS_FH   = 0;            // 16384 fine hist bins (key >> 18)
constexpr int WS_THR  = 16384;        // threshold key
constexpr int WS_ECNT = 16385;        // edge counter
constexpr int WS_CCNT = 16386;        // candidate counter
constexpr int WS_EI   = 16448;
constexpr int WS_EJ   = WS_EI + 8192;
constexpr int WS_EV   = WS_EJ + 8192;
constexpr int WS_CK   = WS_EV + 8192; // candidate keys
constexpr int WS_CI   = WS_CK + 8192; // candidate packed idx (i<<12|j)
constexpr int EDGE_CAP = 8192;
constexpr int CAND_CAP = 8192;

__global__ void init_kernel(unsigned* ws) {
  int i = blockIdx.x * 1024 + threadIdx.x;
  if (i < 16448) ws[i] = 0;  // hist + THR + ECNT + CCNT (+ pad)
}

// ---- adj = relu(tanh(E E^T)); 64x64 tile, 4x4/thread, K=64 in LDS ----
__global__ __launch_bounds__(256) void gemm_adj_kernel(const float* __restrict__ E,
                                                       float* __restrict__ adj) {
  __shared__ float4 As4[64 * 16];
  __shared__ float4 Bs4[64 * 16];
  const float4* E4 = (const float4*)E;
  const int bi = blockIdx.y * 64;
  const int bj = blockIdx.x * 64;
  const int tid = threadIdx.x;

#pragma unroll
  for (int it = 0; it < 4; ++it) {
    int row = (tid >> 4) + it * 16;
    int g = tid & 15;
    int sw = g ^ ((row >> 2) & 7);          // quad swizzle
    As4[row * 16 + sw] = E4[(bi + row) * 16 + g];
    Bs4[row * 16 + sw] = E4[(bj + row) * 16 + g];
  }
  __syncthreads();

  const int i0 = (tid >> 4) * 4;
  const int j0 = (tid & 15) * 4;
  const int sa = (i0 >> 2) & 7;
  const int sb = (j0 >> 2) & 7;
  float acc[4][4] = {};
#pragma unroll
  for (int k4 = 0; k4 < 16; ++k4) {
    float4 av[4], bv[4];
#pragma unroll
    for (int r = 0; r < 4; ++r) av[r] = As4[(i0 + r) * 16 + (k4 ^ sa)];
#pragma unroll
    for (int c = 0; c < 4; ++c) bv[c] = Bs4[(j0 + c) * 16 + (k4 ^ sb)];
#pragma unroll
    for (int r = 0; r < 4; ++r)
#pragma unroll
      for (int c = 0; c < 4; ++c) {
        acc[r][c] += av[r].x * bv[c].x;
        acc[r][c] += av[r].y * bv[c].y;
        acc[r][c] += av[r].z * bv[c].z;
        acc[r][c] += av[r].w * bv[c].w;
      }
  }
#pragma unroll
  for (int r = 0; r < 4; ++r) {
    float4 o;
    float* p = &o.x;
#pragma unroll
    for (int c = 0; c < 4; ++c) {
      float t = tanhf(acc[r][c]);
      p[c] = t > 0.f ? t : 0.f;
    }
    *(float4*)(adj + (size_t)(bi + i0 + r) * NN + bj + j0) = o;
  }
}

// ---- Per-region Prim, exact reference semantics; W block staged in LDS ----
__global__ __launch_bounds__(128) void mst_kernel(const float* __restrict__ adj, unsigned* ws) {
  __shared__ float W[RR * RR];   // 64 KB
  __shared__ float swk[2];
  __shared__ int   swi[2];
  const int g = blockIdx.x;
  const int t = threadIdx.x;
  const int base = g * RR;
  float4* W4 = (float4*)W;
  const float4* A4 = (const float4*)adj;
  int*   ei = (int*)(ws + WS_EI);
  int*   ej = (int*)(ws + WS_EJ);
  float* ev = (float*)(ws + WS_EV);

#pragma unroll
  for (int n = 0; n < 32; ++n) {
    int f = t + 128 * n;
    int row = f >> 5, c4 = f & 31;
    W4[f] = A4[(size_t)(base + row) * (NN / 4) + base / 4 + c4];
  }
  __syncthreads();

  float a0 = W[t];
  bool in_tree = (t == 0);
  float key = (t != 0 && a0 > 0.f) ? -a0 : BIGF;
  int parent = 0;
  const int lane = t & 63, wid = t >> 6;

  for (int it = 0; it < RR - 1; ++it) {
    float km = in_tree ? BIGF : key;
    float k_ = km; int i_ = t;
#pragma unroll
    for (int off = 32; off > 0; off >>= 1) {
      float ok = __shfl_down(k_, off);
      int   oi = __shfl_down(i_, off);
      if (ok < k_ || (ok == k_ && oi < i_)) { k_ = ok; i_ = oi; }
    }
    if (lane == 0) { swk[wid] = k_; swi[wid] = i_; }
    __syncthreads();
    float k0 = swk[0], k1 = swk[1];
    int idx0 = swi[0], idx1 = swi[1];
    __syncthreads();
    int u; float kmu;
    if (k1 < k0 || (k1 == k0 && idx1 < idx0)) { kmu = k1; u = idx1; }
    else                                      { kmu = k0; u = idx0; }

    if (t == u) {
      if (kmu < 0.5f * BIGF) {
        unsigned slot = atomicAdd(ws + WS_ECNT, 1u);
        if (slot < EDGE_CAP) { ei[slot] = base + u; ej[slot] = base + parent; ev[slot] = -kmu; }
      }
      in_tree = true;
    }
    float av = W[u * RR + t];
    float w = (av > 0.f && t != u) ? -av : BIGF;
    if (!in_tree && w < key) { key = w; parent = u; }
  }
}

// ---- 14-bit histogram over candidates (j>i, cross-region, v>0) ----
__global__ __launch_bounds__(256) void hist_kernel(const float* __restrict__ adj, unsigned* ws) {
  __shared__ unsigned h[16384];
  for (int b = threadIdx.x; b < 16384; b += 256) h[b] = 0;
  __syncthreads();
  const float4* a4 = (const float4*)adj;
  const long total4 = (long)NN * NN / 4;
  const long stride = (long)gridDim.x * blockDim.x;
  for (long e = (long)blockIdx.x * blockDim.x + threadIdx.x; e < total4; e += stride) {
    float4 v = a4[e];
    int b = (int)(e << 2);
    int i = b >> 12, j0 = b & 4095, ri = i >> 7;
    float comp[4] = {v.x, v.y, v.z, v.w};
#pragma unroll
    for (int c = 0; c < 4; ++c) {
      int j = j0 + c;
      float x = comp[c];
      if (j <= i || ((j >> 7) == ri) || !(x > 0.f)) continue;
      atomicAdd(&h[__float_as_uint(x) >> 18], 1u);
    }
  }
  __syncthreads();
  for (int b = threadIdx.x; b < 16384; b += 256) {
    unsigned c = h[b];
    if (c) atomicAdd(&ws[WS_FH + b], c);
  }
}

// ---- find bin containing the k-th largest; thr = bin floor ----
__global__ void scan_kernel(unsigned* ws, const int* budget) {
  __shared__ unsigned coarse[256];
  int t = threadIdx.x;
  unsigned sum = 0;
  for (int f = 0; f < 64; ++f) sum += ws[WS_FH + t * 64 + f];
  coarse[t] = sum;
  __syncthreads();
  if (t == 0) {
    unsigned k = (unsigned)budget[0];
    unsigned cum = 0;
    int cb = 0;
    for (int d = 255; d >= 0; --d) {
      unsigned c = coarse[d];
      if (cum + c >= k) { cb = d; break; }
      cum += c;
    }
    int fb = cb * 64;
    for (int f = 63; f >= 0; --f) {
      unsigned c = ws[WS_FH + cb * 64 + f];
      if (cum + c >= k) { fb = cb * 64 + f; break; }
      cum += c;
    }
    ws[WS_THR] = ((unsigned)fb) << 18;
  }
}

// ---- gather all candidates with key >= thr ----
__global__ __launch_bounds__(256) void collect_kernel(const float* __restrict__ adj, unsigned* ws) {
  const unsigned thr = ws[WS_THR];
  const float4* a4 = (const float4*)adj;
  const long total4 = (long)NN * NN / 4;
  const long stride = (long)gridDim.x * blockDim.x;
  for (long e = (long)blockIdx.x * blockDim.x + threadIdx.x; e < total4; e += stride) {
    float4 v = a4[e];
    int b = (int)(e << 2);
    int i = b >> 12, j0 = b & 4095, ri = i >> 7;
    float comp[4] = {v.x, v.y, v.z, v.w};
#pragma unroll
    for (int c = 0; c < 4; ++c) {
      int j = j0 + c;
      float x = comp[c];
      if (j <= i || ((j >> 7) == ri) || !(x > 0.f)) continue;
      unsigned key = __float_as_uint(x);
      if (key >= thr) {
        unsigned slot = atomicAdd(ws + WS_CCNT, 1u);
        if (slot < CAND_CAP) {
          ws[WS_CK + slot] = key;
          ws[WS_CI + slot] = (unsigned)((i << 12) | j);
        }
      }
    }
  }
}

// ---- exact top-k among candidates: bitonic sort of (key<<32 | ~idx) ----
__global__ __launch_bounds__(1024) void topk_kernel(unsigned* ws, const int* budget) {
  __shared__ unsigned long long s[8192];
  const int t = threadIdx.x;
  unsigned n = ws[WS_CCNT];
  if (n > CAND_CAP) n = CAND_CAP;
  const unsigned k = (unsigned)budget[0];
  for (int i = t; i < 8192; i += 1024) {
    unsigned long long v = 0ull;
    if (i < (int)n) {
      unsigned key = ws[WS_CK + i];
      unsigned idx = ws[WS_CI + i];
      v = ((unsigned long long)key << 32) | (unsigned long long)(0x00FFFFFFu - idx);
    }
    s[i] = v;
  }
  for (unsigned size = 2; size <= 8192; size <<= 1)
    for (unsigned stride = size >> 1; stride > 0; stride >>= 1) {
      __syncthreads();
      for (unsigned i = t; i < 4096; i += 1024) {
        unsigned lo = ((i & ~(stride - 1)) << 1) | (i & (stride - 1));
        unsigned hi = lo | stride;
        bool up = ((lo & size) == 0);
        unsigned long long a = s[lo], b = s[hi];
        if ((a > b) == up) { s[lo] = b; s[hi] = a; }
      }
    }
  __syncthreads();
  // ascending; the k largest sit at the tail
  for (int p = t; p < (int)k; p += 1024) {
    unsigned long long v = s[8191 - p];
    if (v == 0ull) continue;
    unsigned key = (unsigned)(v >> 32);
    unsigned idx = 0x00FFFFFFu - (unsigned)(v & 0xFFFFFFFFull);
    unsigned slot = atomicAdd(ws + WS_ECNT, 1u);
    if (slot < EDGE_CAP) {
      ((int*)(ws + WS_EI))[slot] = (int)(idx >> 12);
      ((int*)(ws + WS_EJ))[slot] = (int)(idx & 4095u);
      ((float*)(ws + WS_EV))[slot] = __uint_as_float(key);
    }
  }
}

__global__ void scatter_kernel(const unsigned* __restrict__ ws, float* __restrict__ out) {
  unsigned cnt = ws[WS_ECNT];
  if (cnt > EDGE_CAP) cnt = EDGE_CAP;
  const int*   ei = (const int*)(ws + WS_EI);
  const int*   ej = (const int*)(ws + WS_EJ);
  const float* ev = (const float*)(ws + WS_EV);
  for (unsigned e = blockIdx.x * blockDim.x + threadIdx.x; e < cnt;
       e += gridDim.x * blockDim.x) {
    int i = ei[e], j = ej[e];
    float v = ev[e];
    out[(size_t)i * NN + j] = v;
    out[(size_t)j * NN + i] = v;
  }
}

extern "C" void kernel_launch(void* const* d_in, const int* in_sizes, int n_in,
                              void* d_out, int out_size, void* d_ws, size_t ws_size,
                              hipStream_t stream) {
  const float* E      = (const float*)d_in[0];
  const int*   budget = (const int*)d_in[2];   // d_in[1] (inter_mask) derived from indices
  float*    adj = (float*)d_out;               // d_out doubles as adj scratch
  unsigned* ws  = (unsigned*)d_ws;

  init_kernel<<<17, 1024, 0, stream>>>(ws);
  gemm_adj_kernel<<<dim3(NN / 64, NN / 64), 256, 0, stream>>>(E, adj);
  mst_kernel<<<GG, RR, 0, stream>>>(adj, ws);
  hist_kernel<<<512, 256, 0, stream>>>(adj, ws);
  scan_kernel<<<1, 256, 0, stream>>>(ws, budget);
  collect_kernel<<<1024, 256, 0, stream>>>(adj, ws);
  topk_kernel<<<1, 1024, 0, stream>>>(ws, budget);
  hipMemsetAsync(d_out, 0, (size_t)NN * NN * sizeof(float), stream);
  scatter_kernel<<<64, 256, 0, stream>>>(ws, adj);
}

// Round 3
// 449.155 us; speedup vs baseline: 2.9701x; 1.1216x over previous
//
#include <hip/hip_runtime.h>

#define NN 4096
#define DD 64
#define RR 128
#define GG 32
constexpr float BIGF = 1e9f;

// ---- workspace layout (u32 words) ----
constexpr int WS_FH   = 0;            // 2048 hist bins (key >> 20, values < 1.0)
constexpr int WS_THR  = 2048;         // threshold key
constexpr int WS_ECNT = 2049;         // edge counter
constexpr int WS_CCNT = 2050;         // candidate counter
constexpr int WS_EI   = 2112;
constexpr int WS_EJ   = WS_EI + 8192;
constexpr int WS_EV   = WS_EJ + 8192;
constexpr int WS_CK   = WS_EV + 8192; // candidate keys
constexpr int WS_CI   = WS_CK + 8192; // candidate packed idx (i<<12|j)
constexpr int EDGE_CAP = 8192;
constexpr int CAND_CAP = 8192;

__global__ void init_kernel(unsigned* ws) {
  int i = threadIdx.x;
  for (int b = i; b < 2112; b += 1024) ws[b] = 0;
}

// ---- adj = relu(tanh(E E^T)) for upper + region-diag tiles; hist fused ----
__global__ __launch_bounds__(256) void gemm_adj_kernel(const float* __restrict__ E,
                                                       float* __restrict__ adj,
                                                       unsigned* __restrict__ ws) {
  const int ti = blockIdx.y, tj = blockIdx.x;
  const bool rdiag = (ti >> 1) == (tj >> 1);
  if (tj < ti && !rdiag) return;                 // lower non-region-diag: never consumed
  const bool cross = (tj >> 1) > (ti >> 1);      // whole tile is cross-region upper

  __shared__ float4 As4[64 * 16];
  __shared__ float4 Bs4[64 * 16];
  __shared__ unsigned h[2048];
  const float4* E4 = (const float4*)E;
  const int bi = ti * 64, bj = tj * 64;
  const int tid = threadIdx.x;

  if (cross)
    for (int b = tid; b < 2048; b += 256) h[b] = 0;

#pragma unroll
  for (int it = 0; it < 4; ++it) {
    int row = (tid >> 4) + it * 16;
    int g = tid & 15;
    int sw = g ^ ((row >> 2) & 7);
    As4[row * 16 + sw] = E4[(bi + row) * 16 + g];
    Bs4[row * 16 + sw] = E4[(bj + row) * 16 + g];
  }
  __syncthreads();

  const int i0 = (tid >> 4) * 4;
  const int j0 = (tid & 15) * 4;
  const int sa = (i0 >> 2) & 7;
  const int sb = (j0 >> 2) & 7;
  float acc[4][4] = {};
#pragma unroll
  for (int k4 = 0; k4 < 16; ++k4) {
    float4 av[4], bv[4];
#pragma unroll
    for (int r = 0; r < 4; ++r) av[r] = As4[(i0 + r) * 16 + (k4 ^ sa)];
#pragma unroll
    for (int c = 0; c < 4; ++c) bv[c] = Bs4[(j0 + c) * 16 + (k4 ^ sb)];
#pragma unroll
    for (int r = 0; r < 4; ++r)
#pragma unroll
      for (int c = 0; c < 4; ++c) {
        acc[r][c] += av[r].x * bv[c].x;
        acc[r][c] += av[r].y * bv[c].y;
        acc[r][c] += av[r].z * bv[c].z;
        acc[r][c] += av[r].w * bv[c].w;
      }
  }
#pragma unroll
  for (int r = 0; r < 4; ++r) {
    float4 o;
    float* p = &o.x;
#pragma unroll
    for (int c = 0; c < 4; ++c) {
      float t = tanhf(acc[r][c]);
      float x = t > 0.f ? t : 0.f;
      p[c] = x;
      if (cross && x > 0.f) atomicAdd(&h[__float_as_uint(x) >> 20], 1u);
    }
    *(float4*)(adj + (size_t)(bi + i0 + r) * NN + bj + j0) = o;
  }
  if (cross) {
    __syncthreads();
    for (int b = tid; b < 2048; b += 256) {
      unsigned c = h[b];
      if (c) atomicAdd(&ws[WS_FH + b], c);
    }
  }
}

// ---- Per-region Prim: ONE wave, 2 nodes/lane, pure-shuffle argmin ----
__global__ __launch_bounds__(64) void mst_kernel(const float* __restrict__ adj, unsigned* ws) {
  __shared__ float W[RR * RR];   // 64 KB
  const int g = blockIdx.x;
  const int l = threadIdx.x;
  const int base = g * RR;
  float4* W4 = (float4*)W;
  const float4* A4 = (const float4*)adj;
  int*   ei = (int*)(ws + WS_EI);
  int*   ej = (int*)(ws + WS_EJ);
  float* ev = (float*)(ws + WS_EV);

#pragma unroll
  for (int n = 0; n < 64; ++n) {
    int f = l + 64 * n;
    W4[f] = A4[(size_t)(base + (f >> 5)) * (NN / 4) + (base >> 2) + (f & 31)];
  }
  __syncthreads();

  const int n0 = l, n1 = l + 64;
  float a0 = W[n0], a1 = W[n1];                 // row 0 of W
  bool in0 = (l == 0), in1 = false;
  float key0 = (n0 != 0 && a0 > 0.f) ? -a0 : BIGF;
  float key1 = (a1 > 0.f) ? -a1 : BIGF;
  int par0 = 0, par1 = 0;

  for (int it = 0; it < RR - 1; ++it) {
    float kA = in0 ? BIGF : key0;
    float kB = in1 ? BIGF : key1;
    float k = kA; int idx = n0;
    if (kB < kA) { k = kB; idx = n1; }          // tie keeps n0 (lower index)
#pragma unroll
    for (int off = 32; off > 0; off >>= 1) {
      float ok = __shfl_xor(k, off);
      int   oi = __shfl_xor(idx, off);
      if (ok < k || (ok == k && oi < idx)) { k = ok; idx = oi; }
    }
    // all lanes agree: u = idx, key = k
    if (l == (idx & 63)) {
      bool valid = k < 0.5f * BIGF;
      int par = (idx >> 6) ? par1 : par0;
      if (valid) {
        unsigned slot = atomicAdd(ws + WS_ECNT, 1u);
        if (slot < EDGE_CAP) { ei[slot] = base + idx; ej[slot] = base + par; ev[slot] = -k; }
      }
      if (idx >> 6) in1 = true; else in0 = true;
    }
    float w0v = W[idx * RR + n0];
    float w1v = W[idx * RR + n1];
    float w0 = (w0v > 0.f && n0 != idx) ? -w0v : BIGF;
    float w1 = (w1v > 0.f && n1 != idx) ? -w1v : BIGF;
    if (!in0 && w0 < key0) { key0 = w0; par0 = idx; }
    if (!in1 && w1 < key1) { key1 = w1; par1 = idx; }
  }
}

// ---- find bin containing the k-th largest; thr = bin floor ----
__global__ __launch_bounds__(1024) void scan_kernel(unsigned* ws, const int* budget) {
  __shared__ unsigned p[1024];
  __shared__ unsigned s[64];
  const int t = threadIdx.x;
  p[t] = ws[WS_FH + 2 * t] + ws[WS_FH + 2 * t + 1];
  __syncthreads();
  if (t < 64) {
    unsigned sum = 0;
    for (int f = 0; f < 16; ++f) sum += p[t * 16 + f];
    s[t] = sum;
  }
  __syncthreads();
  if (t == 0) {
    unsigned k = (unsigned)budget[0];
    unsigned cum = 0;
    int sb = 0;
    for (int d = 63; d >= 0; --d) {
      if (cum + s[d] >= k) { sb = d; break; }
      cum += s[d];
    }
    int pb = sb * 16;
    for (int d = sb * 16 + 15; d >= sb * 16; --d) {
      if (cum + p[d] >= k) { pb = d; break; }
      cum += p[d];
    }
    int fb = pb * 2;
    for (int d = pb * 2 + 1; d >= pb * 2; --d) {
      if (cum + ws[WS_FH + d] >= k) { fb = d; break; }
      cum += ws[WS_FH + d];
    }
    ws[WS_THR] = ((unsigned)fb) << 20;
  }
}

// ---- gather all candidates with key >= thr (upper cross-region only) ----
__global__ __launch_bounds__(256) void collect_kernel(const float* __restrict__ adj, unsigned* ws) {
  const unsigned thr = ws[WS_THR];
  const float4* a4 = (const float4*)adj;
  const long total4 = (long)NN * NN / 4;
  const long stride = (long)gridDim.x * blockDim.x;
  for (long e = (long)blockIdx.x * blockDim.x + threadIdx.x; e < total4; e += stride) {
    int b = (int)(e << 2);
    int i = b >> 12, j0 = b & 4095;
    if ((j0 >> 7) <= (i >> 7)) continue;        // skip before load: lower/intra region
    float4 v = a4[e];
    float comp[4] = {v.x, v.y, v.z, v.w};
#pragma unroll
    for (int c = 0; c < 4; ++c) {
      float x = comp[c];
      if (!(x > 0.f)) continue;
      unsigned key = __float_as_uint(x);
      if (key >= thr) {
        unsigned slot = atomicAdd(ws + WS_CCNT, 1u);
        if (slot < CAND_CAP) {
          ws[WS_CK + slot] = key;
          ws[WS_CI + slot] = (unsigned)((i << 12) | (j0 + c));
        }
      }
    }
  }
}

// ---- exact top-k among candidates: bitonic sort of (key<<32 | ~idx) ----
__global__ __launch_bounds__(1024) void topk_kernel(unsigned* ws, const int* budget) {
  __shared__ unsigned long long s[8192];
  const int t = threadIdx.x;
  unsigned n = ws[WS_CCNT];
  if (n > CAND_CAP) n = CAND_CAP;
  const unsigned k = (unsigned)budget[0];
  for (int i = t; i < 8192; i += 1024) {
    unsigned long long v = 0ull;
    if (i < (int)n) {
      unsigned key = ws[WS_CK + i];
      unsigned idx = ws[WS_CI + i];
      v = ((unsigned long long)key << 32) | (unsigned long long)(0x00FFFFFFu - idx);
    }
    s[i] = v;
  }
  for (unsigned size = 2; size <= 8192; size <<= 1)
    for (unsigned stride = size >> 1; stride > 0; stride >>= 1) {
      __syncthreads();
      for (unsigned i = t; i < 4096; i += 1024) {
        unsigned lo = ((i & ~(stride - 1)) << 1) | (i & (stride - 1));
        unsigned hi = lo | stride;
        bool up = ((lo & size) == 0);
        unsigned long long a = s[lo], b = s[hi];
        if ((a > b) == up) { s[lo] = b; s[hi] = a; }
      }
    }
  __syncthreads();
  for (int p = t; p < (int)k; p += 1024) {
    unsigned long long v = s[8191 - p];
    if (v == 0ull) continue;
    unsigned key = (unsigned)(v >> 32);
    unsigned idx = 0x00FFFFFFu - (unsigned)(v & 0xFFFFFFFFull);
    unsigned slot = atomicAdd(ws + WS_ECNT, 1u);
    if (slot < EDGE_CAP) {
      ((int*)(ws + WS_EI))[slot] = (int)(idx >> 12);
      ((int*)(ws + WS_EJ))[slot] = (int)(idx & 4095u);
      ((float*)(ws + WS_EV))[slot] = __uint_as_float(key);
    }
  }
}

__global__ void scatter_kernel(const unsigned* __restrict__ ws, float* __restrict__ out) {
  unsigned cnt = ws[WS_ECNT];
  if (cnt > EDGE_CAP) cnt = EDGE_CAP;
  const int*   ei = (const int*)(ws + WS_EI);
  const int*   ej = (const int*)(ws + WS_EJ);
  const float* ev = (const float*)(ws + WS_EV);
  for (unsigned e = blockIdx.x * blockDim.x + threadIdx.x; e < cnt;
       e += gridDim.x * blockDim.x) {
    int i = ei[e], j = ej[e];
    float v = ev[e];
    out[(size_t)i * NN + j] = v;
    out[(size_t)j * NN + i] = v;
  }
}

extern "C" void kernel_launch(void* const* d_in, const int* in_sizes, int n_in,
                              void* d_out, int out_size, void* d_ws, size_t ws_size,
                              hipStream_t stream) {
  const float* E      = (const float*)d_in[0];
  const int*   budget = (const int*)d_in[2];   // d_in[1] (inter_mask) derived from indices
  float*    adj = (float*)d_out;               // d_out doubles as adj scratch
  unsigned* ws  = (unsigned*)d_ws;

  init_kernel<<<1, 1024, 0, stream>>>(ws);
  gemm_adj_kernel<<<dim3(NN / 64, NN / 64), 256, 0, stream>>>(E, adj, ws);
  mst_kernel<<<GG, 64, 0, stream>>>(adj, ws);
  scan_kernel<<<1, 1024, 0, stream>>>(ws, budget);
  collect_kernel<<<1024, 256, 0, stream>>>(adj, ws);
  topk_kernel<<<1, 1024, 0, stream>>>(ws, budget);
  hipMemsetAsync(d_out, 0, (size_t)NN * NN * sizeof(float), stream);
  scatter_kernel<<<64, 256, 0, stream>>>(ws, adj);
}

// Round 4
// 314.956 us; speedup vs baseline: 4.2356x; 1.4261x over previous
//
#include <hip/hip_runtime.h>

#define NN 4096
#define DD 64
#define RR 128
#define GG 32
constexpr float BIGF = 1e9f;
constexpr unsigned BIGH = 0xCE6E6B28u;   // order-transform of bits(1e9f)

// ---- workspace layout (u32 words) ----
constexpr int WS_FH   = 0;               // 2048 hist bins (key >> 20)
constexpr int WS_THR  = 2048;            // kth-bin floor key
constexpr int WS_BHI  = 2049;            // kth-bin ceiling key (exclusive)
constexpr int WS_REM  = 2050;            // how many needed from the kth bin
constexpr int WS_ECNT = 2051;            // inter edge counter
constexpr int WS_CCNT = 2052;            // in-bin candidate counter
constexpr int WS_MIJ  = 2112;            // 4096 mst slots, packed (i<<12)|j or ~0
constexpr int WS_MV   = WS_MIJ + 4096;   // 4096 mst edge values
constexpr int WS_EI   = WS_MV + 4096;
constexpr int WS_EJ   = WS_EI + 8192;
constexpr int WS_EV   = WS_EJ + 8192;
constexpr int WS_CK   = WS_EV + 8192;
constexpr int WS_CI   = WS_CK + 8192;
constexpr int EDGE_CAP = 8192;
constexpr int CAND_CAP = 8192;

__global__ void init_kernel(unsigned* ws) {
  for (int b = threadIdx.x; b < 2112; b += 1024) ws[b] = 0;
}

// ---- adj = relu(tanh(E E^T)) for upper + region-diag tiles; hist fused ----
// NOTE: numeric path bit-exact vs np reference (absmax 0.0) — do not perturb.
__global__ __launch_bounds__(256) void gemm_adj_kernel(const float* __restrict__ E,
                                                       float* __restrict__ adj,
                                                       unsigned* __restrict__ ws) {
  const int ti = blockIdx.y, tj = blockIdx.x;
  const bool rdiag = (ti >> 1) == (tj >> 1);
  if (tj < ti && !rdiag) return;
  const bool cross = (tj >> 1) > (ti >> 1);

  __shared__ float4 As4[64 * 16];
  __shared__ float4 Bs4[64 * 16];
  __shared__ unsigned h[2048];
  const float4* E4 = (const float4*)E;
  const int bi = ti * 64, bj = tj * 64;
  const int tid = threadIdx.x;

  if (cross)
    for (int b = tid; b < 2048; b += 256) h[b] = 0;

#pragma unroll
  for (int it = 0; it < 4; ++it) {
    int row = (tid >> 4) + it * 16;
    int g = tid & 15;
    int sw = g ^ ((row >> 2) & 7);
    As4[row * 16 + sw] = E4[(bi + row) * 16 + g];
    Bs4[row * 16 + sw] = E4[(bj + row) * 16 + g];
  }
  __syncthreads();

  const int i0 = (tid >> 4) * 4;
  const int j0 = (tid & 15) * 4;
  const int sa = (i0 >> 2) & 7;
  const int sb = (j0 >> 2) & 7;
  float acc[4][4] = {};
#pragma unroll
  for (int k4 = 0; k4 < 16; ++k4) {
    float4 av[4], bv[4];
#pragma unroll
    for (int r = 0; r < 4; ++r) av[r] = As4[(i0 + r) * 16 + (k4 ^ sa)];
#pragma unroll
    for (int c = 0; c < 4; ++c) bv[c] = Bs4[(j0 + c) * 16 + (k4 ^ sb)];
#pragma unroll
    for (int r = 0; r < 4; ++r)
#pragma unroll
      for (int c = 0; c < 4; ++c) {
        acc[r][c] += av[r].x * bv[c].x;
        acc[r][c] += av[r].y * bv[c].y;
        acc[r][c] += av[r].z * bv[c].z;
        acc[r][c] += av[r].w * bv[c].w;
      }
  }
#pragma unroll
  for (int r = 0; r < 4; ++r) {
    float4 o;
    float* p = &o.x;
#pragma unroll
    for (int c = 0; c < 4; ++c) {
      float t = tanhf(acc[r][c]);
      float x = t > 0.f ? t : 0.f;
      p[c] = x;
      if (cross && x > 0.f) atomicAdd(&h[__float_as_uint(x) >> 20], 1u);
    }
    *(float4*)(adj + (size_t)(bi + i0 + r) * NN + bj + j0) = o;
  }
  if (cross) {
    __syncthreads();
    for (int b = tid; b < 2048; b += 256) {
      unsigned c = h[b];
      if (c) atomicAdd(&ws[WS_FH + b], c);
    }
  }
}

// ---- (key,idx) lexicographic min reduction helpers ----
template <int CTRL>
__device__ __forceinline__ void dpp_min(unsigned& kh, unsigned& kl) {
  unsigned oh = (unsigned)__builtin_amdgcn_update_dpp(0, (int)kh, CTRL, 0xF, 0xF, false);
  unsigned ol = (unsigned)__builtin_amdgcn_update_dpp(0, (int)kl, CTRL, 0xF, 0xF, false);
  unsigned long long o = ((unsigned long long)oh << 32) | ol;
  unsigned long long c = ((unsigned long long)kh << 32) | kl;
  if (o < c) { kh = oh; kl = ol; }
}
__device__ __forceinline__ void shfl_min(unsigned& kh, unsigned& kl, int m) {
  unsigned oh = (unsigned)__shfl_xor((int)kh, m);
  unsigned ol = (unsigned)__shfl_xor((int)kl, m);
  unsigned long long o = ((unsigned long long)oh << 32) | ol;
  unsigned long long c = ((unsigned long long)kh << 32) | kl;
  if (o < c) { kh = oh; kl = ol; }
}
// transform: key = -a (a>0) -> ~bits(a) & 0x7FFFFFFF ; monotone with float order
__device__ __forceinline__ unsigned xfneg(float a) {
  return ~__float_as_uint(a) & 0x7FFFFFFFu;
}

// ---- Per-region Prim: one wave, 2 nodes/lane, DPP argmin, no atomics ----
__global__ __launch_bounds__(64) void mst_kernel(const float* __restrict__ adj, unsigned* ws) {
  __shared__ float W[RR * RR];           // 64 KB
  __shared__ unsigned emij[RR];
  __shared__ float emv[RR];
  const int g = blockIdx.x, l = threadIdx.x, base = g * RR;
  float4* W4 = (float4*)W;
  const float4* A4 = (const float4*)adj;

#pragma unroll
  for (int n = 0; n < 64; ++n) {
    int f = l + 64 * n;
    W4[f] = A4[(size_t)(base + (f >> 5)) * (NN / 4) + (base >> 2) + (f & 31)];
  }
  emij[l] = 0xFFFFFFFFu;
  emij[l + 64] = 0xFFFFFFFFu;
  __syncthreads();

  const int n0 = l, n1 = l + 64;
  float a0 = W[n0], a1 = W[n1];          // row 0
  unsigned key0 = (n0 != 0 && a0 > 0.f) ? xfneg(a0) : BIGH;
  unsigned key1 = (a1 > 0.f) ? xfneg(a1) : BIGH;
  bool in0 = (l == 0), in1 = false;
  int par0 = 0, par1 = 0;

  for (int it = 0; it < RR - 1; ++it) {
    unsigned kA = in0 ? BIGH : key0;
    unsigned kB = in1 ? BIGH : key1;
    unsigned kh, kl;
    if (kB < kA) { kh = kB; kl = (unsigned)n1; }   // tie keeps n0 (lower idx)
    else         { kh = kA; kl = (unsigned)n0; }
    dpp_min<0xB1>(kh, kl);    // quad_perm xor1
    dpp_min<0x4E>(kh, kl);    // quad_perm xor2
    dpp_min<0x141>(kh, kl);   // row_half_mirror (== xor4 after xor1,2)
    dpp_min<0x140>(kh, kl);   // row_mirror      (== xor8 after previous)
    shfl_min(kh, kl, 16);
    shfl_min(kh, kl, 32);
    const int u = (int)kl;

    if (l == (u & 63)) {      // edge emission: LDS only, off critical path
      unsigned pij = 0xFFFFFFFFu;
      float pv = 0.f;
      if ((int)kh >= 0) {     // real key (top bit clear), not BIG
        int par = (u >> 6) ? par1 : par0;
        pij = ((unsigned)(base + u) << 12) | (unsigned)(base + par);
        pv = __uint_as_float(~kh & 0x7FFFFFFFu);   // exact adj value bits
      }
      emij[it] = pij;
      emv[it] = pv;
    }
    in0 = in0 || (u == n0);
    in1 = in1 || (u == n1);
    float w0v = W[u * RR + n0];
    float w1v = W[u * RR + n1];
    unsigned w0 = (w0v > 0.f && n0 != u) ? xfneg(w0v) : BIGH;
    unsigned w1 = (w1v > 0.f && n1 != u) ? xfneg(w1v) : BIGH;
    if (!in0 && w0 < key0) { key0 = w0; par0 = u; }
    if (!in1 && w1 < key1) { key1 = w1; par1 = u; }
  }
  __syncthreads();
  ws[WS_MIJ + base + l] = emij[l];
  ws[WS_MIJ + base + 64 + l] = emij[64 + l];
  ((float*)(ws + WS_MV))[base + l] = emv[l];
  ((float*)(ws + WS_MV))[base + 64 + l] = emv[64 + l];
}

// ---- locate kth bin; emit bin_lo / bin_hi / rem ----
__global__ __launch_bounds__(1024) void scan_kernel(unsigned* ws, const int* budget) {
  __shared__ unsigned p[1024];
  __shared__ unsigned s[64];
  const int t = threadIdx.x;
  p[t] = ws[WS_FH + 2 * t] + ws[WS_FH + 2 * t + 1];
  __syncthreads();
  if (t < 64) {
    unsigned sum = 0;
    for (int f = 0; f < 16; ++f) sum += p[t * 16 + f];
    s[t] = sum;
  }
  __syncthreads();
  if (t == 0) {
    unsigned k = (unsigned)budget[0];
    unsigned cum = 0;
    int sb = 0;
    for (int d = 63; d >= 0; --d) {
      if (cum + s[d] >= k) { sb = d; break; }
      cum += s[d];
    }
    int pb = sb * 16;
    for (int d = sb * 16 + 15; d >= sb * 16; --d) {
      if (cum + p[d] >= k) { pb = d; break; }
      cum += p[d];
    }
    int fb = pb * 2;
    for (int d = pb * 2 + 1; d >= pb * 2; --d) {
      if (cum + ws[WS_FH + d] >= k) { fb = d; break; }
      cum += ws[WS_FH + d];
    }
    ws[WS_THR] = ((unsigned)fb) << 20;
    ws[WS_BHI] = ((unsigned)(fb + 1)) << 20;
    ws[WS_REM] = k - cum;     // needed from the kth bin
  }
}

// ---- above-bin -> straight to edge list; in-bin -> candidates ----
__global__ __launch_bounds__(256) void collect_kernel(const float* __restrict__ adj, unsigned* ws) {
  const unsigned tlo = ws[WS_THR], thi = ws[WS_BHI];
  const float4* a4 = (const float4*)adj;
  const long total4 = (long)NN * NN / 4;
  const long stride = (long)gridDim.x * blockDim.x;
  for (long e = (long)blockIdx.x * blockDim.x + threadIdx.x; e < total4; e += stride) {
    int b = (int)(e << 2);
    int i = b >> 12, j0 = b & 4095;
    if ((j0 >> 7) <= (i >> 7)) continue;   // lower / intra-region: skip before load
    float4 v = a4[e];
    float comp[4] = {v.x, v.y, v.z, v.w};
#pragma unroll
    for (int c = 0; c < 4; ++c) {
      float x = comp[c];
      if (!(x > 0.f)) continue;
      unsigned key = __float_as_uint(x);
      if (key < tlo) continue;
      if (key >= thi) {
        unsigned slot = atomicAdd(ws + WS_ECNT, 1u);
        if (slot < EDGE_CAP) {
          ((int*)(ws + WS_EI))[slot] = i;
          ((int*)(ws + WS_EJ))[slot] = j0 + c;
          ((float*)(ws + WS_EV))[slot] = x;
        }
      } else {
        unsigned s2 = atomicAdd(ws + WS_CCNT, 1u);
        if (s2 < CAND_CAP) {
          ws[WS_CK + s2] = key;
          ws[WS_CI + s2] = (unsigned)((i << 12) | (j0 + c));
        }
      }
    }
  }
}

// ---- sort only the kth bin's ties; append top-rem (lowest idx first) ----
__global__ __launch_bounds__(1024) void topk_kernel(unsigned* ws) {
  __shared__ unsigned long long s[CAND_CAP];
  const int t = threadIdx.x;
  unsigned n = ws[WS_CCNT];
  if (n > CAND_CAP) n = CAND_CAP;
  const unsigned rem = ws[WS_REM];
  unsigned m = 2;
  while (m < n) m <<= 1;
  for (int i = t; i < (int)m; i += 1024) {
    unsigned long long v = 0ull;
    if (i < (int)n)
      v = ((unsigned long long)ws[WS_CK + i] << 32) |
          (unsigned long long)(0x00FFFFFFu - ws[WS_CI + i]);
    s[i] = v;
  }
  for (unsigned size = 2; size <= m; size <<= 1)
    for (unsigned stride = size >> 1; stride; stride >>= 1) {
      __syncthreads();
      for (unsigned i = t; i < m / 2; i += 1024) {
        unsigned lo = ((i & ~(stride - 1)) << 1) | (i & (stride - 1));
        unsigned hi = lo | stride;
        bool up = ((lo & size) == 0);
        unsigned long long a = s[lo], b = s[hi];
        if ((a > b) == up) { s[lo] = b; s[hi] = a; }
      }
    }
  __syncthreads();
  for (unsigned p = t; p < rem; p += 1024) {
    unsigned long long v = s[m - 1 - p];
    if (v == 0ull) continue;
    unsigned key = (unsigned)(v >> 32);
    unsigned idx = 0x00FFFFFFu - (unsigned)(v & 0xFFFFFFFFull);
    unsigned slot = atomicAdd(ws + WS_ECNT, 1u);
    if (slot < EDGE_CAP) {
      ((int*)(ws + WS_EI))[slot] = (int)(idx >> 12);
      ((int*)(ws + WS_EJ))[slot] = (int)(idx & 4095u);
      ((float*)(ws + WS_EV))[slot] = __uint_as_float(key);
    }
  }
}

__global__ void scatter_kernel(const unsigned* __restrict__ ws, float* __restrict__ out) {
  unsigned cnt = ws[WS_ECNT];
  if (cnt > EDGE_CAP) cnt = EDGE_CAP;
  const int tot = 4096 + (int)cnt;
  for (int e = blockIdx.x * blockDim.x + threadIdx.x; e < tot;
       e += gridDim.x * blockDim.x) {
    int i, j;
    float v;
    if (e < 4096) {
      unsigned pij = ws[WS_MIJ + e];
      if (pij == 0xFFFFFFFFu) continue;
      i = (int)(pij >> 12);
      j = (int)(pij & 4095u);
      v = ((const float*)(ws + WS_MV))[e];
    } else {
      int q = e - 4096;
      i = ((const int*)(ws + WS_EI))[q];
      j = ((const int*)(ws + WS_EJ))[q];
      v = ((const float*)(ws + WS_EV))[q];
    }
    out[(size_t)i * NN + j] = v;
    out[(size_t)j * NN + i] = v;
  }
}

extern "C" void kernel_launch(void* const* d_in, const int* in_sizes, int n_in,
                              void* d_out, int out_size, void* d_ws, size_t ws_size,
                              hipStream_t stream) {
  const float* E      = (const float*)d_in[0];
  const int*   budget = (const int*)d_in[2];
  float*    adj = (float*)d_out;       // d_out doubles as adj scratch
  unsigned* ws  = (unsigned*)d_ws;

  init_kernel<<<1, 1024, 0, stream>>>(ws);
  gemm_adj_kernel<<<dim3(NN / 64, NN / 64), 256, 0, stream>>>(E, adj, ws);
  mst_kernel<<<GG, 64, 0, stream>>>(adj, ws);
  scan_kernel<<<1, 1024, 0, stream>>>(ws, budget);
  collect_kernel<<<1024, 256, 0, stream>>>(adj, ws);
  topk_kernel<<<1, 1024, 0, stream>>>(ws);
  hipMemsetAsync(d_out, 0, (size_t)NN * NN * sizeof(float), stream);
  scatter_kernel<<<64, 256, 0, stream>>>(ws, adj);
}